// Round 11
// baseline (158.950 us; speedup 1.0000x reference)
//
#include <hip/hip_runtime.h>
#include <math.h>

#define NB 16
#define NS 4096
#define ND 1024
#define NH 16
#define LUTN 4096
#define NC 32            // s-chunks (R5 best-known config)
#define SC (NS / NC)     // 128 rows per block
#define RG 8             // rows per group (LDS broadcast granularity)
#define NG (SC / RG)     // 16 groups
#define NREP 2           // instrumentation: 2 identical passes -> dur > fill dur
                         // so k_fused's rocprof counters appear in the top-5

#define KF   651.8986469044033f      // LUT_SIZE / (2*pi)
#define PHIF 1.6180339887498949f
#define REVF 2.44140625e-4f          // 1/4096 (exact) — LUT step in revolutions
#define INV_SCALE (1.0f / 11.313708498984761f)  // 1/sqrt(2*dh)

// workspace layout, in floats
#define OFF_P     0          // P[NC][NB][NH][ND] f32 = 8388608 floats (33.5 MB)
#define OFF_ZPART 8388608    // [NC][NB][NH] = 8192
#define OFF_INVZ  8396800    // [NB*NH] = 256

// fused scores + unnormalized per-head context, single pass over cached.
// 256 thr, float4; e-broadcast via 1KB dbuf LDS; one barrier per 8 rows.
__global__ __launch_bounds__(256) void k_fused(const float* __restrict__ cached,
                                               const float* __restrict__ x,
                                               const float* __restrict__ t,
                                               const float* __restrict__ wq,
                                               const float* __restrict__ bq,
                                               const float* __restrict__ wk,
                                               const float* __restrict__ bk,
                                               float* __restrict__ ws) {
    __shared__ float se[2][RG][16];    // e broadcast, double-buffered (1 KB)
    int tid = threadIdx.x;
    int b = blockIdx.x >> 5;           // / NC
    int c = blockIdx.x & (NC - 1);
    int s0 = c * SC;
    int m = tid * 4;

    // key params producing LUT index directly: idx = rint(v*krK + kbK)
    float4 wkv = *(const float4*)(wk + m);
    float4 kbv = *(const float4*)(bk + m);
    float4 krK, kbK;
    krK.x = KF / (1.0f + fabsf(wkv.x));
    krK.y = KF / (1.0f + fabsf(wkv.y));
    krK.z = KF / (1.0f + fabsf(wkv.z));
    krK.w = KF / (1.0f + fabsf(wkv.w));
    kbK.x = kbv.x * KF;
    kbK.y = kbv.y * KF;
    kbK.z = kbv.z * KF;
    kbK.w = kbv.w * KF;

    // query phase as pre-negated REVOLUTIONS on the LUT grid (exact: idx*2^-12)
    float tphi = t[b] * PHIF;
    float4 xv = *(const float4*)(x + b * ND + m);
    float4 wqv = *(const float4*)(wq + m);
    float4 bqv = *(const float4*)(bq + m);
    float jq0 = -rintf((xv.x / (1.0f + fabsf(wqv.x)) + bqv.x + tphi) * KF) * REVF;
    float jq1 = -rintf((xv.y / (1.0f + fabsf(wqv.y)) + bqv.y + tphi) * KF) * REVF;
    float jq2 = -rintf((xv.z / (1.0f + fabsf(wqv.z)) + bqv.z + tphi) * KF) * REVF;
    float jq3 = -rintf((xv.w / (1.0f + fabsf(wqv.w)) + bqv.w + tphi) * KF) * REVF;

    float4 acch[16];
    float zacc;
    const float* base = cached + ((size_t)b * NS + s0) * ND + m;
    float4 v[RG];

    for (int rep = 0; rep < NREP; ++rep) {
        #pragma unroll
        for (int h = 0; h < 16; ++h) acch[h] = make_float4(0.f, 0.f, 0.f, 0.f);
        zacc = 0.f;

        for (int g = 0; g < NG; ++g) {
            const float* bp = base + (size_t)g * (RG * ND);
            #pragma unroll
            for (int r = 0; r < RG; ++r)
                v[r] = *(const float4*)(bp + (size_t)r * ND);

            // cos((idx_k - idx_q)*2pi/4096): v_cos takes revolutions
            #pragma unroll
            for (int r = 0; r < RG; ++r) {
                float a0 = fmaf(rintf(fmaf(v[r].x, krK.x, kbK.x)), REVF, jq0);
                float a1 = fmaf(rintf(fmaf(v[r].y, krK.y, kbK.y)), REVF, jq1);
                float a2 = fmaf(rintf(fmaf(v[r].z, krK.z, kbK.z)), REVF, jq2);
                float a3 = fmaf(rintf(fmaf(v[r].w, krK.w, kbK.w)), REVF, jq3);
                float p = (__builtin_amdgcn_cosf(a0) + __builtin_amdgcn_cosf(a1)) +
                          (__builtin_amdgcn_cosf(a2) + __builtin_amdgcn_cosf(a3));
                p += __shfl_xor(p, 1, 16);
                p += __shfl_xor(p, 2, 16);
                p += __shfl_xor(p, 4, 16);
                p += __shfl_xor(p, 8, 16);
                float e = __expf(p * INV_SCALE);  // |score| <= 5.66, no max pass
                zacc += e;
                if ((tid & 15) == 0) se[g & 1][r][tid >> 4] = e;
            }
            __syncthreads();   // se(g) visible; dbuf keeps 1 barrier/group safe
            #pragma unroll
            for (int r = 0; r < RG; ++r) {
                const float4* s4 = (const float4*)se[g & 1][r];
                float4 ea = s4[0], eb = s4[1], ec = s4[2], ed = s4[3];
                float4 vv = v[r];
#define ACC4(i, e) acch[i].x = fmaf(e, vv.x, acch[i].x); \
                   acch[i].y = fmaf(e, vv.y, acch[i].y); \
                   acch[i].z = fmaf(e, vv.z, acch[i].z); \
                   acch[i].w = fmaf(e, vv.w, acch[i].w);
                ACC4(0, ea.x)  ACC4(1, ea.y)  ACC4(2, ea.z)  ACC4(3, ea.w)
                ACC4(4, eb.x)  ACC4(5, eb.y)  ACC4(6, eb.z)  ACC4(7, eb.w)
                ACC4(8, ec.x)  ACC4(9, ec.y)  ACC4(10, ec.z) ACC4(11, ec.w)
                ACC4(12, ed.x) ACC4(13, ed.y) ACC4(14, ed.z) ACC4(15, ed.w)
#undef ACC4
            }
        }
    }

    // write per-head context partials, coalesced per h (values identical per rep)
    float* P = ws + OFF_P + (size_t)(c * NB + b) * (NH * ND) + m;
    #pragma unroll
    for (int h = 0; h < 16; ++h)
        *(float4*)(P + h * ND) = acch[h];
    if ((tid & 15) == 0)
        ws[OFF_ZPART + (c * NB + b) * NH + (tid >> 4)] = zacc;
}

__global__ __launch_bounds__(256) void k_z(float* __restrict__ ws) {
    int i = threadIdx.x;   // b*NH + h
    float s = 0.f;
    #pragma unroll
    for (int c = 0; c < NC; ++c) s += ws[OFF_ZPART + c * 256 + i];
    ws[OFF_INVZ + i] = 1.0f / s;
}

__global__ __launch_bounds__(256) void k_out(const float* __restrict__ t,
                                             const float* __restrict__ wo,
                                             const float* __restrict__ bo,
                                             const float* __restrict__ osc,
                                             const float* __restrict__ ws,
                                             float* __restrict__ out) {
    __shared__ float red[4][64];
    int bid = blockIdx.x;          // NB*16 = 256
    int b = bid >> 4, mc = bid & 15;
    int tid = threadIdx.x;
    int cq = tid >> 6, ml = tid & 63;
    int m = mc * 64 + ml;
    const float* P = ws + OFF_P;
    float ctx = 0.f;
    #pragma unroll
    for (int h = 0; h < NH; ++h) {
        float s = 0.f;
        #pragma unroll
        for (int i = 0; i < NC / 4; ++i) {
            int c = cq * (NC / 4) + i;
            s += P[(size_t)(c * NB + b) * (NH * ND) + h * ND + m];
        }
        ctx = fmaf(s, ws[OFF_INVZ + b * NH + h], ctx);
    }
    red[cq][ml] = ctx;
    __syncthreads();
    if (cq == 0) {
        ctx = ((red[0][ml] + red[1][ml]) + (red[2][ml] + red[3][ml]));
        float theta = ctx / (1.0f + fabsf(wo[m])) + bo[m] + t[b] * PHIF;
        int idx = ((int)rintf(theta * KF)) & (LUTN - 1);
        float ang = (float)idx * (2.0f * 3.14159265358979323846f / LUTN);
        // precise libm trig: bit-matches the np table entries
        out[b * ND + m] = osc[m] * (cosf(ang) + sinf(ang));
    }
}

extern "C" void kernel_launch(void* const* d_in, const int* in_sizes, int n_in,
                              void* d_out, int out_size, void* d_ws, size_t ws_size,
                              hipStream_t stream) {
    const float* x      = (const float*)d_in[0];
    const float* cached = (const float*)d_in[1];
    const float* t      = (const float*)d_in[2];
    const float* wq     = (const float*)d_in[3];
    const float* bq     = (const float*)d_in[4];
    const float* wk     = (const float*)d_in[5];
    const float* bk     = (const float*)d_in[6];
    const float* wo     = (const float*)d_in[7];
    const float* bo     = (const float*)d_in[8];
    const float* osc    = (const float*)d_in[9];
    float* ws  = (float*)d_ws;
    float* out = (float*)d_out;

    k_fused<<<NB * NC, 256, 0, stream>>>(cached, x, t, wq, bq, wk, bk, ws);
    k_z<<<1, 256, 0, stream>>>(ws);
    k_out<<<NB * (ND / 64), 256, 0, stream>>>(t, wo, bo, osc, ws, out);
}

// Round 12
// 92.085 us; speedup vs baseline: 1.7261x; 1.7261x over previous
//
#include <hip/hip_runtime.h>
#include <math.h>

#define NB 16
#define NS 4096
#define ND 1024
#define NH 16
#define LUTN 4096
#define NC 32            // s-chunks (grid = NB*NC = 512 blocks, 2/CU)
#define SC (NS / NC)     // 128 rows per block
#define RG 16            // rows per group (R12: 8->16, halves barrier count)
#define NG (SC / RG)     // 8 groups

#define KF   651.8986469044033f      // LUT_SIZE / (2*pi)
#define PHIF 1.6180339887498949f
#define REVF 2.44140625e-4f          // 1/4096 (exact) — LUT step in revolutions
#define INV_SCALE (1.0f / 11.313708498984761f)  // 1/sqrt(2*dh)

// workspace layout, in floats
#define OFF_P     0          // P[NC][NB][NH][ND] f32 = 8388608 floats (33.5 MB)
#define OFF_ZPART 8388608    // [NC][NB][NH] = 8192
#define OFF_INVZ  8396800    // [NB*NH] = 256

// Sum over each 16-lane group using DPP row_shr (pure VALU, ~16 cyc) instead
// of 4 serialized ds_swizzle shuffles (~160 cyc on the LDS pipe). After the
// 4 steps, lane 16k+15 holds the sum of lanes 16k..16k+15.
__device__ __forceinline__ float dpp_reduce16(float p) {
    int y;
    y = __builtin_amdgcn_update_dpp(0, __float_as_int(p), 0x111, 0xF, 0xF, true);
    p += __int_as_float(y);   // + lane(i-1)
    y = __builtin_amdgcn_update_dpp(0, __float_as_int(p), 0x112, 0xF, 0xF, true);
    p += __int_as_float(y);   // + lanes(i-3..i-2)
    y = __builtin_amdgcn_update_dpp(0, __float_as_int(p), 0x114, 0xF, 0xF, true);
    p += __int_as_float(y);   // + lanes(i-7..i-4)
    y = __builtin_amdgcn_update_dpp(0, __float_as_int(p), 0x118, 0xF, 0xF, true);
    p += __int_as_float(y);   // + lanes(i-15..i-8): lane 15 = full row sum
    return p;
}

// fused scores + unnormalized per-head context, single pass over cached.
__global__ __launch_bounds__(256) void k_fused(const float* __restrict__ cached,
                                               const float* __restrict__ x,
                                               const float* __restrict__ t,
                                               const float* __restrict__ wq,
                                               const float* __restrict__ bq,
                                               const float* __restrict__ wk,
                                               const float* __restrict__ bk,
                                               float* __restrict__ ws) {
    __shared__ float se[2][RG][16];    // e broadcast, double-buffered (2 KB)
    int tid = threadIdx.x;
    int b = blockIdx.x >> 5;           // / NC
    int c = blockIdx.x & (NC - 1);
    int s0 = c * SC;
    int m = tid * 4;

    // key params producing LUT index directly: idx = rint(v*krK + kbK)
    float4 wkv = *(const float4*)(wk + m);
    float4 kbv = *(const float4*)(bk + m);
    float4 krK, kbK;
    krK.x = KF / (1.0f + fabsf(wkv.x));
    krK.y = KF / (1.0f + fabsf(wkv.y));
    krK.z = KF / (1.0f + fabsf(wkv.z));
    krK.w = KF / (1.0f + fabsf(wkv.w));
    kbK.x = kbv.x * KF;
    kbK.y = kbv.y * KF;
    kbK.z = kbv.z * KF;
    kbK.w = kbv.w * KF;

    // query phase as pre-negated REVOLUTIONS on the LUT grid (exact: idx*2^-12)
    float tphi = t[b] * PHIF;
    float4 xv = *(const float4*)(x + b * ND + m);
    float4 wqv = *(const float4*)(wq + m);
    float4 bqv = *(const float4*)(bq + m);
    float jq0 = -rintf((xv.x / (1.0f + fabsf(wqv.x)) + bqv.x + tphi) * KF) * REVF;
    float jq1 = -rintf((xv.y / (1.0f + fabsf(wqv.y)) + bqv.y + tphi) * KF) * REVF;
    float jq2 = -rintf((xv.z / (1.0f + fabsf(wqv.z)) + bqv.z + tphi) * KF) * REVF;
    float jq3 = -rintf((xv.w / (1.0f + fabsf(wqv.w)) + bqv.w + tphi) * KF) * REVF;

    float4 acch[16];
    #pragma unroll
    for (int h = 0; h < 16; ++h) acch[h] = make_float4(0.f, 0.f, 0.f, 0.f);
    float zacc = 0.f;

    const float* base = cached + ((size_t)b * NS + s0) * ND + m;
    float4 v[RG];

    for (int g = 0; g < NG; ++g) {
        const float* bp = base + (size_t)g * (RG * ND);
        #pragma unroll
        for (int r = 0; r < RG; ++r)
            v[r] = *(const float4*)(bp + (size_t)r * ND);   // 16 KB/wave in flight

        // cos((idx_k - idx_q)*2pi/4096): v_cos takes revolutions (cos(S0*2pi))
        #pragma unroll
        for (int r = 0; r < RG; ++r) {
            float a0 = fmaf(rintf(fmaf(v[r].x, krK.x, kbK.x)), REVF, jq0);
            float a1 = fmaf(rintf(fmaf(v[r].y, krK.y, kbK.y)), REVF, jq1);
            float a2 = fmaf(rintf(fmaf(v[r].z, krK.z, kbK.z)), REVF, jq2);
            float a3 = fmaf(rintf(fmaf(v[r].w, krK.w, kbK.w)), REVF, jq3);
            float p = (__builtin_amdgcn_cosf(a0) + __builtin_amdgcn_cosf(a1)) +
                      (__builtin_amdgcn_cosf(a2) + __builtin_amdgcn_cosf(a3));
            p = dpp_reduce16(p);                 // lane 15 of each 16-group
            float e = __expf(p * INV_SCALE);     // |score| <= 5.66, no max pass
            zacc += e;                           // valid only in lanes 15 mod 16
            if ((tid & 15) == 15) se[g & 1][r][tid >> 4] = e;
        }
        __syncthreads();   // se(g) visible; dbuf makes 1 barrier/group WAR-safe
        #pragma unroll
        for (int r = 0; r < RG; ++r) {
            const float4* s4 = (const float4*)se[g & 1][r];
            float4 ea = s4[0], eb = s4[1], ec = s4[2], ed = s4[3];
            float4 vv = v[r];
#define ACC4(i, e) acch[i].x = fmaf(e, vv.x, acch[i].x); \
                   acch[i].y = fmaf(e, vv.y, acch[i].y); \
                   acch[i].z = fmaf(e, vv.z, acch[i].z); \
                   acch[i].w = fmaf(e, vv.w, acch[i].w);
            ACC4(0, ea.x)  ACC4(1, ea.y)  ACC4(2, ea.z)  ACC4(3, ea.w)
            ACC4(4, eb.x)  ACC4(5, eb.y)  ACC4(6, eb.z)  ACC4(7, eb.w)
            ACC4(8, ec.x)  ACC4(9, ec.y)  ACC4(10, ec.z) ACC4(11, ec.w)
            ACC4(12, ed.x) ACC4(13, ed.y) ACC4(14, ed.z) ACC4(15, ed.w)
#undef ACC4
        }
    }

    // write per-head context partials, coalesced per h
    float* P = ws + OFF_P + (size_t)(c * NB + b) * (NH * ND) + m;
    #pragma unroll
    for (int h = 0; h < 16; ++h)
        *(float4*)(P + h * ND) = acch[h];
    if ((tid & 15) == 15)
        ws[OFF_ZPART + (c * NB + b) * NH + (tid >> 4)] = zacc;
}

__global__ __launch_bounds__(256) void k_z(float* __restrict__ ws) {
    int i = threadIdx.x;   // b*NH + h
    float s = 0.f;
    #pragma unroll
    for (int c = 0; c < NC; ++c) s += ws[OFF_ZPART + c * 256 + i];
    ws[OFF_INVZ + i] = 1.0f / s;
}

__global__ __launch_bounds__(256) void k_out(const float* __restrict__ t,
                                             const float* __restrict__ wo,
                                             const float* __restrict__ bo,
                                             const float* __restrict__ osc,
                                             const float* __restrict__ ws,
                                             float* __restrict__ out) {
    __shared__ float red[4][64];
    int bid = blockIdx.x;          // NB*16 = 256
    int b = bid >> 4, mc = bid & 15;
    int tid = threadIdx.x;
    int cq = tid >> 6, ml = tid & 63;
    int m = mc * 64 + ml;
    const float* P = ws + OFF_P;
    float ctx = 0.f;
    #pragma unroll
    for (int h = 0; h < NH; ++h) {
        float s = 0.f;
        #pragma unroll
        for (int i = 0; i < NC / 4; ++i) {
            int c = cq * (NC / 4) + i;
            s += P[(size_t)(c * NB + b) * (NH * ND) + h * ND + m];
        }
        ctx = fmaf(s, ws[OFF_INVZ + b * NH + h], ctx);
    }
    red[cq][ml] = ctx;
    __syncthreads();
    if (cq == 0) {
        ctx = ((red[0][ml] + red[1][ml]) + (red[2][ml] + red[3][ml]));
        float theta = ctx / (1.0f + fabsf(wo[m])) + bo[m] + t[b] * PHIF;
        int idx = ((int)rintf(theta * KF)) & (LUTN - 1);
        float ang = (float)idx * (2.0f * 3.14159265358979323846f / LUTN);
        // precise libm trig: bit-matches the np table entries
        out[b * ND + m] = osc[m] * (cosf(ang) + sinf(ang));
    }
}

extern "C" void kernel_launch(void* const* d_in, const int* in_sizes, int n_in,
                              void* d_out, int out_size, void* d_ws, size_t ws_size,
                              hipStream_t stream) {
    const float* x      = (const float*)d_in[0];
    const float* cached = (const float*)d_in[1];
    const float* t      = (const float*)d_in[2];
    const float* wq     = (const float*)d_in[3];
    const float* bq     = (const float*)d_in[4];
    const float* wk     = (const float*)d_in[5];
    const float* bk     = (const float*)d_in[6];
    const float* wo     = (const float*)d_in[7];
    const float* bo     = (const float*)d_in[8];
    const float* osc    = (const float*)d_in[9];
    float* ws  = (float*)d_ws;
    float* out = (float*)d_out;

    k_fused<<<NB * NC, 256, 0, stream>>>(cached, x, t, wq, bq, wk, bk, ws);
    k_z<<<1, 256, 0, stream>>>(ws);
    k_out<<<NB * (ND / 64), 256, 0, stream>>>(t, wo, bo, osc, ws, out);
}